// Round 1
// baseline (509.596 us; speedup 1.0000x reference)
//
#include <hip/hip_runtime.h>
#include <hip/hip_bf16.h>
#include <stdint.h>

// Problem dims (fixed by setup_inputs)
#define T_DIM 2048
#define I_DIM 4096
#define O_DIM 4096
#define R_DIM 16
#define QBLK  32

typedef __bf16 bf16x8 __attribute__((ext_vector_type(8)));
typedef float  floatx4 __attribute__((ext_vector_type(4)));
typedef unsigned short ushort_t;

__device__ __forceinline__ ushort_t f2bf(float f) {
  unsigned u = __float_as_uint(f);
  u += 0x7FFFu + ((u >> 16) & 1u);   // round-to-nearest-even
  return (ushort_t)(u >> 16);
}

__device__ __forceinline__ float dot4(float4 a, float4 b) {
  return a.x * b.x + a.y * b.y + a.z * b.z + a.w * b.w;
}

// ---------------- prep_x: f32 -> bf16 (8 elems/thread) ----------------
__global__ __launch_bounds__(256) void k_prep_x(const float* __restrict__ x,
                                                ushort_t* __restrict__ xb) {
  int idx = blockIdx.x * 256 + threadIdx.x;   // 8-element chunk id
  const float4* xp = (const float4*)x;
  float4 a = xp[idx * 2], b = xp[idx * 2 + 1];
  union { ushort_t u[8]; uint4 v; } r;
  r.u[0] = f2bf(a.x); r.u[1] = f2bf(a.y); r.u[2] = f2bf(a.z); r.u[3] = f2bf(a.w);
  r.u[4] = f2bf(b.x); r.u[5] = f2bf(b.y); r.u[6] = f2bf(b.z); r.u[7] = f2bf(b.w);
  ((uint4*)xb)[idx] = r.v;
}

// ---------------- prep_w: dequant int32 codes -> bf16 W ----------------
__global__ __launch_bounds__(256) void k_prep_w(const int* __restrict__ q,
                                                const float* __restrict__ scales,
                                                ushort_t* __restrict__ wb) {
  int idx = blockIdx.x * 256 + threadIdx.x;   // 8-element chunk id
  int o  = idx >> 9;                          // I/8 = 512 chunks per row
  int i0 = (idx & 511) * 8;                   // 8-aligned -> same quant block
  float s = scales[o * (I_DIM / QBLK) + (i0 >> 5)];
  const int4* qp = (const int4*)(q + (size_t)o * I_DIM + i0);
  int4 q0 = qp[0], q1 = qp[1];
  union { ushort_t u[8]; uint4 v; } r;
  r.u[0] = f2bf((float)(q0.x - 8) * s); r.u[1] = f2bf((float)(q0.y - 8) * s);
  r.u[2] = f2bf((float)(q0.z - 8) * s); r.u[3] = f2bf((float)(q0.w - 8) * s);
  r.u[4] = f2bf((float)(q1.x - 8) * s); r.u[5] = f2bf((float)(q1.y - 8) * s);
  r.u[6] = f2bf((float)(q1.z - 8) * s); r.u[7] = f2bf((float)(q1.w - 8) * s);
  ((uint4*)wb)[idx] = r.v;
}

// ---------------- xd = alpha * (x @ down^T)  [T,16] f32 ----------------
// 8 tokens/block, down chunk staged in LDS, 32 threads per token.
__global__ __launch_bounds__(256) void k_xd(const float* __restrict__ x,
                                            const float* __restrict__ down,
                                            const float* __restrict__ alphap,
                                            float* __restrict__ xd) {
  __shared__ float ds[16 * 512];              // 32 KB: down[0:16][ib:ib+512)
  const int tid = threadIdx.x;
  const int tl = tid >> 5, s = tid & 31;
  const int t = blockIdx.x * 8 + tl;
  float acc[16];
#pragma unroll
  for (int r = 0; r < 16; ++r) acc[r] = 0.f;

  for (int c = 0; c < 8; ++c) {
    const int ib = c * 512;
    __syncthreads();
#pragma unroll
    for (int j = 0; j < 8; ++j) {
      int e = j * 256 + tid;                  // float4 slot, 2048 total
      int r = e >> 7, col = e & 127;
      ((float4*)ds)[e] = ((const float4*)(down + (size_t)r * I_DIM + ib))[col];
    }
    __syncthreads();
#pragma unroll
    for (int j = 0; j < 4; ++j) {
      float4 xv = ((const float4*)(x + (size_t)t * I_DIM + ib))[s + 32 * j];
#pragma unroll
      for (int r = 0; r < 16; ++r) {
        float4 dv = ((const float4*)ds)[r * 128 + s + 32 * j];
        acc[r] += dot4(xv, dv);
      }
    }
  }
  const float al = alphap[0];
#pragma unroll
  for (int r = 0; r < 16; ++r) {
    float v = acc[r];
    v += __shfl_down(v, 16, 32);
    v += __shfl_down(v, 8, 32);
    v += __shfl_down(v, 4, 32);
    v += __shfl_down(v, 2, 32);
    v += __shfl_down(v, 1, 32);
    if (s == 0) xd[t * 16 + r] = v * al;
  }
}

// ---------------- main GEMM: y = xb @ wb^T + lora-epilogue + bias ------
// 128x128 tile, BK=64, 4 waves (2x2), 4x4 mfma_16x16x32_bf16 per wave.
// LDS tiles staged with global_load_lds width=16; XOR swizzle on the
// 8-bf16 segment index (col8 ^= row&7) to spread fragment reads over banks.
__global__ __launch_bounds__(256) void k_gemm(const ushort_t* __restrict__ xb,
                                              const ushort_t* __restrict__ wb,
                                              const float* __restrict__ bias,
                                              const float* __restrict__ xd,
                                              const float* __restrict__ up,
                                              float* __restrict__ y) {
  __shared__ __align__(16) ushort_t As[128 * 64];   // 16 KB
  __shared__ __align__(16) ushort_t Bs[128 * 64];   // 16 KB
  const int tid = threadIdx.x;
  const int oT = blockIdx.x * 128, tT = blockIdx.y * 128;
  const int w = tid >> 6, l = tid & 63;
  const int wm = w >> 1, wn = w & 1;
  const int quad = l >> 4, m16 = l & 15;

  floatx4 acc[4][4] = {};

  for (int kt = 0; kt < I_DIM / 64; ++kt) {
    const int k0 = kt * 64;
#pragma unroll
    for (int it = 0; it < 4; ++it) {
      int seg = it * 256 + tid;               // LDS 16B-segment index
      int r = seg >> 3;
      int cg = (seg & 7) ^ (r & 7);           // swizzled global col-segment
      __builtin_amdgcn_global_load_lds(
          (const __attribute__((address_space(1))) char*)(xb + (size_t)(tT + r) * I_DIM + k0 + cg * 8),
          (__attribute__((address_space(3))) char*)(As + seg * 8), 16, 0, 0);
      __builtin_amdgcn_global_load_lds(
          (const __attribute__((address_space(1))) char*)(wb + (size_t)(oT + r) * I_DIM + k0 + cg * 8),
          (__attribute__((address_space(3))) char*)(Bs + seg * 8), 16, 0, 0);
    }
    asm volatile("s_waitcnt vmcnt(0)" ::: "memory");
    __syncthreads();

#pragma unroll
    for (int ks2 = 0; ks2 < 2; ++ks2) {       // two K=32 steps per BK=64
      const int c = ks2 * 4 + quad;           // k-segment (8 bf16) index
      bf16x8 af[4], bfr[4];
#pragma unroll
      for (int im = 0; im < 4; ++im) {
        int m = wm * 64 + im * 16 + m16;
        af[im] = *(const bf16x8*)(As + (m * 8 + (c ^ (m & 7))) * 8);
      }
#pragma unroll
      for (int in_ = 0; in_ < 4; ++in_) {
        int n = wn * 64 + in_ * 16 + m16;
        bfr[in_] = *(const bf16x8*)(Bs + (n * 8 + (c ^ (n & 7))) * 8);
      }
#pragma unroll
      for (int im = 0; im < 4; ++im)
#pragma unroll
        for (int in_ = 0; in_ < 4; ++in_)
          acc[im][in_] = __builtin_amdgcn_mfma_f32_16x16x32_bf16(
              af[im], bfr[in_], acc[im][in_], 0, 0, 0);
    }
    __syncthreads();
  }

  // Epilogue: y[t][o] = acc + dot16(xd[t], up[o]) + bias[o]
  // C/D layout: row = quad*4+reg, col = lane&15 (m89-verified).
#pragma unroll
  for (int im = 0; im < 4; ++im) {
#pragma unroll
    for (int reg = 0; reg < 4; ++reg) {
      int t = tT + wm * 64 + im * 16 + quad * 4 + reg;
      const float4* xr = (const float4*)(xd + t * 16);
      float4 x0 = xr[0], x1 = xr[1], x2 = xr[2], x3 = xr[3];
#pragma unroll
      for (int in_ = 0; in_ < 4; ++in_) {
        int o = oT + wn * 64 + in_ * 16 + m16;
        const float4* ur = (const float4*)(up + (size_t)o * R_DIM);
        float lv = dot4(x0, ur[0]) + dot4(x1, ur[1]) +
                   dot4(x2, ur[2]) + dot4(x3, ur[3]);
        y[(size_t)t * O_DIM + o] = acc[im][in_][reg] + lv + bias[o];
      }
    }
  }
}

extern "C" void kernel_launch(void* const* d_in, const int* in_sizes, int n_in,
                              void* d_out, int out_size, void* d_ws, size_t ws_size,
                              hipStream_t stream) {
  const float* x      = (const float*)d_in[0];
  const int*   q      = (const int*)d_in[1];
  const float* scales = (const float*)d_in[2];
  const float* up     = (const float*)d_in[3];
  const float* down   = (const float*)d_in[4];
  const float* alpha  = (const float*)d_in[5];
  const float* bias   = (const float*)d_in[6];
  float* y = (float*)d_out;

  // ws layout: xb bf16 [T,I] (16 MB) | wb bf16 [O,I] (32 MB) | xd f32 [T,16]
  ushort_t* xb = (ushort_t*)d_ws;
  ushort_t* wb = (ushort_t*)((char*)d_ws + (size_t)T_DIM * I_DIM * 2);
  float*    xd = (float*)((char*)d_ws + (size_t)T_DIM * I_DIM * 2 + (size_t)O_DIM * I_DIM * 2);

  hipLaunchKernelGGL(k_prep_x, dim3((T_DIM * I_DIM) / 8 / 256), dim3(256), 0, stream, x, xb);
  hipLaunchKernelGGL(k_prep_w, dim3((O_DIM * I_DIM) / 8 / 256), dim3(256), 0, stream, q, scales, wb);
  hipLaunchKernelGGL(k_xd, dim3(T_DIM / 8), dim3(256), 0, stream, x, down, alpha, xd);
  hipLaunchKernelGGL(k_gemm, dim3(O_DIM / 128, T_DIM / 128), dim3(256), 0, stream,
                     xb, wb, bias, xd, up, y);
}

// Round 2
// 508.925 us; speedup vs baseline: 1.0013x; 1.0013x over previous
//
#include <hip/hip_runtime.h>
#include <hip/hip_bf16.h>
#include <stdint.h>

// Problem dims (fixed by setup_inputs)
#define T_DIM 2048
#define I_DIM 4096
#define O_DIM 4096
#define R_DIM 16
#define QBLK  32

typedef __bf16 bf16x8 __attribute__((ext_vector_type(8)));
typedef float  floatx4 __attribute__((ext_vector_type(4)));
typedef unsigned short ushort_t;

__device__ __forceinline__ ushort_t f2bf(float f) {
  unsigned u = __float_as_uint(f);
  u += 0x7FFFu + ((u >> 16) & 1u);   // round-to-nearest-even
  return (ushort_t)(u >> 16);
}

__device__ __forceinline__ float dot4(float4 a, float4 b) {
  return a.x * b.x + a.y * b.y + a.z * b.z + a.w * b.w;
}

// ---------------- prep_x: f32 -> bf16 (8 elems/thread) ----------------
__global__ __launch_bounds__(256) void k_prep_x(const float* __restrict__ x,
                                                ushort_t* __restrict__ xb) {
  int idx = blockIdx.x * 256 + threadIdx.x;   // 8-element chunk id
  const float4* xp = (const float4*)x;
  float4 a = xp[idx * 2], b = xp[idx * 2 + 1];
  union { ushort_t u[8]; uint4 v; } r;
  r.u[0] = f2bf(a.x); r.u[1] = f2bf(a.y); r.u[2] = f2bf(a.z); r.u[3] = f2bf(a.w);
  r.u[4] = f2bf(b.x); r.u[5] = f2bf(b.y); r.u[6] = f2bf(b.z); r.u[7] = f2bf(b.w);
  ((uint4*)xb)[idx] = r.v;
}

// ---------------- prep_w: dequant int32 codes -> bf16 W ----------------
__global__ __launch_bounds__(256) void k_prep_w(const int* __restrict__ q,
                                                const float* __restrict__ scales,
                                                ushort_t* __restrict__ wb) {
  int idx = blockIdx.x * 256 + threadIdx.x;   // 8-element chunk id
  int o  = idx >> 9;                          // I/8 = 512 chunks per row
  int i0 = (idx & 511) * 8;                   // 8-aligned -> same quant block
  float s = scales[o * (I_DIM / QBLK) + (i0 >> 5)];
  const int4* qp = (const int4*)(q + (size_t)o * I_DIM + i0);
  int4 q0 = qp[0], q1 = qp[1];
  union { ushort_t u[8]; uint4 v; } r;
  r.u[0] = f2bf((float)(q0.x - 8) * s); r.u[1] = f2bf((float)(q0.y - 8) * s);
  r.u[2] = f2bf((float)(q0.z - 8) * s); r.u[3] = f2bf((float)(q0.w - 8) * s);
  r.u[4] = f2bf((float)(q1.x - 8) * s); r.u[5] = f2bf((float)(q1.y - 8) * s);
  r.u[6] = f2bf((float)(q1.z - 8) * s); r.u[7] = f2bf((float)(q1.w - 8) * s);
  ((uint4*)wb)[idx] = r.v;
}

// ---------------- xd = alpha * (x @ down^T)  [T,16] f32 ----------------
__global__ __launch_bounds__(256) void k_xd(const float* __restrict__ x,
                                            const float* __restrict__ down,
                                            const float* __restrict__ alphap,
                                            float* __restrict__ xd) {
  __shared__ float ds[16 * 512];              // 32 KB: down[0:16][ib:ib+512)
  const int tid = threadIdx.x;
  const int tl = tid >> 5, s = tid & 31;
  const int t = blockIdx.x * 8 + tl;
  float acc[16];
#pragma unroll
  for (int r = 0; r < 16; ++r) acc[r] = 0.f;

  for (int c = 0; c < 8; ++c) {
    const int ib = c * 512;
    __syncthreads();
#pragma unroll
    for (int j = 0; j < 8; ++j) {
      int e = j * 256 + tid;                  // float4 slot, 2048 total
      int r = e >> 7, col = e & 127;
      ((float4*)ds)[e] = ((const float4*)(down + (size_t)r * I_DIM + ib))[col];
    }
    __syncthreads();
#pragma unroll
    for (int j = 0; j < 4; ++j) {
      float4 xv = ((const float4*)(x + (size_t)t * I_DIM + ib))[s + 32 * j];
#pragma unroll
      for (int r = 0; r < 16; ++r) {
        float4 dv = ((const float4*)ds)[r * 128 + s + 32 * j];
        acc[r] += dot4(xv, dv);
      }
    }
  }
  const float al = alphap[0];
#pragma unroll
  for (int r = 0; r < 16; ++r) {
    float v = acc[r];
    v += __shfl_down(v, 16, 32);
    v += __shfl_down(v, 8, 32);
    v += __shfl_down(v, 4, 32);
    v += __shfl_down(v, 2, 32);
    v += __shfl_down(v, 1, 32);
    if (s == 0) xd[t * 16 + r] = v * al;
  }
}

// ---------------- main GEMM: y = xb @ wb^T + lora-epilogue + bias ------
// 128x128 tile, BK=64, 4 waves (2x2), 4x4 mfma_16x16x32_bf16 per wave.
// Staging: global_load_lds width=16 with WAVE-UNIFORM LDS base (the HW
// semantic is base + lane*16; a divergent LDS pointer operand was the R1
// disaster). XOR swizzle on the 8-bf16 segment index spreads fragment
// reads across banks (0 conflicts measured in R1).
__global__ __launch_bounds__(256) void k_gemm(const ushort_t* __restrict__ xb,
                                              const ushort_t* __restrict__ wb,
                                              const float* __restrict__ bias,
                                              const float* __restrict__ xd,
                                              const float* __restrict__ up,
                                              float* __restrict__ y) {
  __shared__ __align__(16) ushort_t As[128 * 64];   // 16 KB
  __shared__ __align__(16) ushort_t Bs[128 * 64];   // 16 KB
  const int tid = threadIdx.x;
  const int oT = blockIdx.x * 128, tT = blockIdx.y * 128;
  const int lane = tid & 63;
  const int wv = __builtin_amdgcn_readfirstlane(tid >> 6);  // wave id, scalar
  const int wm = wv >> 1, wn = wv & 1;
  const int quad = lane >> 4, m16 = lane & 15;

  // Per-lane global source segment for each staging instruction:
  // seg = seg_base + lane, seg_base = (it*4 + wv)*64 (wave-uniform).
  // row r = seg>>3, swizzled col cg = (seg&7) ^ (r&7).
  floatx4 acc[4][4] = {};

  for (int kt = 0; kt < I_DIM / 64; ++kt) {
    const int k0 = kt * 64;
#pragma unroll
    for (int it = 0; it < 4; ++it) {
      const int seg_base = (it * 4 + wv) * 64;          // wave-uniform
      const int seg = seg_base + lane;
      const int r = seg >> 3;
      const int cg = (seg & 7) ^ (r & 7);
      __builtin_amdgcn_global_load_lds(
          (const __attribute__((address_space(1))) char*)(xb + (size_t)(tT + r) * I_DIM + k0 + cg * 8),
          (__attribute__((address_space(3))) char*)(As + seg_base * 8), 16, 0, 0);
      __builtin_amdgcn_global_load_lds(
          (const __attribute__((address_space(1))) char*)(wb + (size_t)(oT + r) * I_DIM + k0 + cg * 8),
          (__attribute__((address_space(3))) char*)(Bs + seg_base * 8), 16, 0, 0);
    }
    asm volatile("s_waitcnt vmcnt(0)" ::: "memory");
    __syncthreads();

#pragma unroll
    for (int ks2 = 0; ks2 < 2; ++ks2) {       // two K=32 steps per BK=64
      const int c = ks2 * 4 + quad;           // k-segment (8 bf16) index
      bf16x8 af[4], bfr[4];
#pragma unroll
      for (int im = 0; im < 4; ++im) {
        int m = wm * 64 + im * 16 + m16;
        af[im] = *(const bf16x8*)(As + (m * 8 + (c ^ (m & 7))) * 8);
      }
#pragma unroll
      for (int in_ = 0; in_ < 4; ++in_) {
        int n = wn * 64 + in_ * 16 + m16;
        bfr[in_] = *(const bf16x8*)(Bs + (n * 8 + (c ^ (n & 7))) * 8);
      }
#pragma unroll
      for (int im = 0; im < 4; ++im)
#pragma unroll
        for (int in_ = 0; in_ < 4; ++in_)
          acc[im][in_] = __builtin_amdgcn_mfma_f32_16x16x32_bf16(
              af[im], bfr[in_], acc[im][in_], 0, 0, 0);
    }
    __syncthreads();
  }

  // Epilogue: y[t][o] = acc + dot16(xd[t], up[o]) + bias[o]
  // C/D layout: row = quad*4+reg, col = lane&15 (m89-verified).
#pragma unroll
  for (int im = 0; im < 4; ++im) {
#pragma unroll
    for (int reg = 0; reg < 4; ++reg) {
      int t = tT + wm * 64 + im * 16 + quad * 4 + reg;
      const float4* xr = (const float4*)(xd + t * 16);
      float4 x0 = xr[0], x1 = xr[1], x2 = xr[2], x3 = xr[3];
#pragma unroll
      for (int in_ = 0; in_ < 4; ++in_) {
        int o = oT + wn * 64 + in_ * 16 + m16;
        const float4* ur = (const float4*)(up + (size_t)o * R_DIM);
        float lv = dot4(x0, ur[0]) + dot4(x1, ur[1]) +
                   dot4(x2, ur[2]) + dot4(x3, ur[3]);
        y[(size_t)t * O_DIM + o] = acc[im][in_][reg] + lv + bias[o];
      }
    }
  }
}

extern "C" void kernel_launch(void* const* d_in, const int* in_sizes, int n_in,
                              void* d_out, int out_size, void* d_ws, size_t ws_size,
                              hipStream_t stream) {
  const float* x      = (const float*)d_in[0];
  const int*   q      = (const int*)d_in[1];
  const float* scales = (const float*)d_in[2];
  const float* up     = (const float*)d_in[3];
  const float* down   = (const float*)d_in[4];
  const float* alpha  = (const float*)d_in[5];
  const float* bias   = (const float*)d_in[6];
  float* y = (float*)d_out;

  // ws layout: xb bf16 [T,I] (16 MB) | wb bf16 [O,I] (32 MB) | xd f32 [T,16]
  ushort_t* xb = (ushort_t*)d_ws;
  ushort_t* wb = (ushort_t*)((char*)d_ws + (size_t)T_DIM * I_DIM * 2);
  float*    xd = (float*)((char*)d_ws + (size_t)T_DIM * I_DIM * 2 + (size_t)O_DIM * I_DIM * 2);

  hipLaunchKernelGGL(k_prep_x, dim3((T_DIM * I_DIM) / 8 / 256), dim3(256), 0, stream, x, xb);
  hipLaunchKernelGGL(k_prep_w, dim3((O_DIM * I_DIM) / 8 / 256), dim3(256), 0, stream, q, scales, wb);
  hipLaunchKernelGGL(k_xd, dim3(T_DIM / 8), dim3(256), 0, stream, x, down, alpha, xd);
  hipLaunchKernelGGL(k_gemm, dim3(O_DIM / 128, T_DIM / 128), dim3(256), 0, stream,
                     xb, wb, bias, xd, up, y);
}